// Round 5
// baseline (1295.108 us; speedup 1.0000x reference)
//
#include <hip/hip_runtime.h>
#include <cstdint>

#define TT 2048
#define NH 15

typedef _Float16 half8 __attribute__((ext_vector_type(8)));
typedef float f32x4 __attribute__((ext_vector_type(4)));
typedef int int4v __attribute__((ext_vector_type(4)));

#define EXP2(x) __builtin_amdgcn_exp2f(x)
#define RCP(x) __builtin_amdgcn_rcpf(x)
// pre-scaled gates: MFMA output d already multiplied by the gate constant
// (A-fragment rows scaled by -log2e for i,f,o and +2*log2e for g)
#define SIGM_PS(d) (RCP(1.0f + EXP2(d)))
#define TANH_PS(d) (fmaf(-2.0f, RCP(1.0f + EXP2(d)), 1.0f))
#define TANHF(x) (fmaf(-2.0f, RCP(1.0f + EXP2((x) * 2.8853900817779268f)), 1.0f))
#define BPERM(addr, v) __builtin_amdgcn_ds_bpermute((addr), (v))
#define PKRTZ_I(a, b) __builtin_bit_cast(int, __builtin_amdgcn_cvt_pkrtz((a), (b)))
#define MFMA16(A, B, C) __builtin_amdgcn_mfma_f32_16x16x32_f16((A), (B), (C), 0, 0, 0)

#define GATES_PS(d0, d1, d2, d3, cref, hout) { \
    const float iv_ = SIGM_PS(d0); \
    const float fv_ = SIGM_PS(d1); \
    const float gv_ = TANH_PS(d2); \
    const float ov_ = SIGM_PS(d3); \
    (cref) = fmaf(fv_, (cref), iv_ * gv_); \
    (hout) = ov_ * TANHF(cref); }

// raw barrier: LDS-ordering only (no vmcnt drain of x-prefetch / out-stores)
#define LDS_BAR() { asm volatile("s_waitcnt lgkmcnt(0)" ::: "memory"); \
                    __builtin_amdgcn_s_barrier(); }

// 6-wave cell x register-pair split, layer-wavefront staggered MFMA LSTM.
// Block = 384 threads = 6 waves, one 16-element batch tile.
//   wave w = 2*cell + pair:  cell c in {0,1,2}, pair p in {0,1}.
//   wave (c,p) runs cell c's 4 gate MFMAs and the GATES math for
//   accumulator regs 2p, 2p+1 (units 4q+2p, 4q+2p+1 per lane quad q).
// 512 blocks x 6 = 3072 waves = 3 waves/SIMD: per-SIMD trans work per step
// is unchanged (60 trans instrs), but the ~430 cy of dependency stall per
// step (barrier -> ds_read -> MFMA -> gate chain) now overlaps other
// waves' issue (R4 ran 1 wave/SIMD: VALUBusy 70%, stalls bare).
//
// Fragment maps (m89-verified): A[m=lane&15][k=(lane>>4)*8+j];
// B[k][n=lane&15]; D col=lane&15, row=(lane>>4)*4+r.
// Interleaved-K: k=8q+j: j<4 "in" unit 4q+j (cell1: u15=x), j>=4 "own"
// unit 4q+j-4 (u15 = bias 1.0). Wave (c,p)'s two h outputs pack into ONE
// dword = exactly one B-fragment word; cross-wave exchange = 1 LDS word
// per wave per step (parity double-buffered, 1 barrier/step).
//
// Stagger at iter i: cell1 -> h1(i), cell2 -> h2(i-1), cell3 -> h3(i-2),
// head (in wave 5) -> y(i-3) via extra MFMA row (w_lin over own-slots,
// b_lin at k31). All reads are lag-1 LDS words:
//   c1 in: W[0] = h1(i-1);  c2 in: W[0] = h1(i-1), own W[1] = h2(i-2);
//   c3 in: W[1] = h2(i-2), own W[2] = h3(i-3)  (also feeds head).
// Warmup peeled: bias hi-half gated 0 until the produced state index >= 0
// (all-zero fragments keep c,h exactly 0). Tail iters' garbage never stored.
__global__ __launch_bounds__(384) __attribute__((amdgpu_waves_per_eu(3)))
void lstm3_split6(const float* __restrict__ input,
                  const float* __restrict__ w_ih1, const float* __restrict__ w_hh1,
                  const float* __restrict__ b_ih1, const float* __restrict__ b_hh1,
                  const float* __restrict__ w_ih2, const float* __restrict__ w_hh2,
                  const float* __restrict__ b_ih2, const float* __restrict__ b_hh2,
                  const float* __restrict__ w_ih3, const float* __restrict__ w_hh3,
                  const float* __restrict__ b_ih3, const float* __restrict__ b_hh3,
                  const float* __restrict__ w_lin, const float* __restrict__ b_lin,
                  float* __restrict__ out);

template<int C, int P, bool HEAD>
__device__ __forceinline__
void role_loop(const int lane, const int n, const int q, const bool q3,
               int (*lds)[3][2][64],
               const half8 a0, const half8 a1, const half8 a2, const half8 a3,
               const half8 ah,
               const float* __restrict__ xrow, float* __restrict__ orow)
{
    constexpr int IC = (C == 0) ? 0 : C - 1;   // "in" word cell index
    constexpr int R0 = 2 * P, R1 = 2 * P + 1;  // accumulator regs we own
    const f32x4 z4 = {0.f, 0.f, 0.f, 0.f};
    float cf0 = 0.f, cf1 = 0.f;
    int myw = 0;                    // our last-written pack (own-pair word)
    float y4[4] = {0.f, 0.f, 0.f, 0.f};
    float xtile = 0.f, xtile_n = 0.f;
    int xp = 0, xp_n = 0, xvp = 0;
    if constexpr (C == 0) {
        xtile = xrow[q]; xtile_n = xrow[4 + q];
        xp = PKRTZ_I(0.f, xtile);        // hi half = f16(x), lo = 0
        xp_n = PKRTZ_I(0.f, xtile_n);
        xvp = BPERM(n * 4, xp);          // packed x(0) broadcast
    }

// One staggered iteration. PH literal 0..3; parity = PH&1 (t0 always even).
#define STEP(PH, G2, G3) { \
    enum { PC_ = (PH) & 1, PP_ = ((PH) & 1) ^ 1 }; \
    int in0, in1, ow0 = 0, ow1 = 0; \
    if constexpr (C == 0) { \
        in0 = (P == 0) ? myw : lds[PP_][0][0][lane]; \
        in1 = (P == 1) ? myw : lds[PP_][0][1][lane]; \
    } else { \
        in0 = lds[PP_][IC][0][lane]; \
        in1 = lds[PP_][IC][1][lane]; \
        ow0 = (P == 0) ? myw : lds[PP_][C][0][lane]; \
        ow1 = (P == 1) ? myw : lds[PP_][C][1][lane]; \
    } \
    int w1_, w2_, w3_; \
    if constexpr (C == 0) { \
        w1_ = q3 ? ((in1 & 0xFFFF) | (xvp & 0xFFFF0000)) : in1; \
        w2_ = 0; \
        w3_ = q3 ? 0x3C000000 : 0; \
    } else { \
        w1_ = in1; \
        w2_ = ow0; \
        const bool gb_ = (C == 1) ? (G2) : (G3); \
        const int hi_ = gb_ ? 0x3C000000 : 0; \
        w3_ = q3 ? ((ow1 & 0xFFFF) | hi_) : ow1; \
    } \
    const int4v bi_ = { in0, w1_, w2_, w3_ }; \
    const half8 Bf_ = __builtin_bit_cast(half8, bi_); \
    const f32x4 D0_ = MFMA16(a0, Bf_, z4); \
    const f32x4 D1_ = MFMA16(a1, Bf_, z4); \
    const f32x4 D2_ = MFMA16(a2, Bf_, z4); \
    const f32x4 D3_ = MFMA16(a3, Bf_, z4); \
    if constexpr (HEAD) { \
        const f32x4 Dh_ = MFMA16(ah, Bf_, z4); \
        y4[((PH) + 1) & 3] = Dh_[0]; \
    } \
    if constexpr (C == 0) { \
        const int xps_ = ((PH) == 3) ? xp_n : xp; \
        xvp = BPERM((((PH) + 1) & 3) * 64 + n * 4, xps_); \
    } \
    float h0_, h1_; \
    GATES_PS(D0_[R0], D1_[R0], D2_[R0], D3_[R0], cf0, h0_); \
    GATES_PS(D0_[R1], D1_[R1], D2_[R1], D3_[R1], cf1, h1_); \
    myw = PKRTZ_I(h0_, h1_); \
    lds[PC_][C][P][lane] = myw; \
    LDS_BAR(); }

    // ---- warmup (i = 0..3): bias gates off until produced index >= 0 ----
    STEP(0, false, false)
    STEP(1, true,  false)
    STEP(2, true,  true)
    STEP(3, true,  true)
    if constexpr (C == 0) {
        xtile = xtile_n; xp = xp_n;
        xtile_n = xrow[8 + q];
        xp_n = PKRTZ_I(0.f, xtile_n);
    }

#pragma unroll 1
    for (int t0 = 4; t0 < TT + 4; t0 += 4) {
        STEP(0, true, true)
        STEP(1, true, true)
        STEP(2, true, true)
        if constexpr (HEAD) {
            if (q == 0)
                *(f32x4*)(orow + (t0 - 4)) = (f32x4){y4[0], y4[1], y4[2], y4[3]};
        }
        STEP(3, true, true)
        if constexpr (C == 0) {
            xtile = xtile_n; xp = xp_n;
            const int tn = t0 + 8 + q;
            xtile_n = xrow[(tn < TT) ? tn : q];   // clamped garbage, unused
            xp_n = PKRTZ_I(0.f, xtile_n);
        }
    }
#undef STEP
}

__global__ __launch_bounds__(384) __attribute__((amdgpu_waves_per_eu(3)))
void lstm3_split6(const float* __restrict__ input,
                  const float* __restrict__ w_ih1, const float* __restrict__ w_hh1,
                  const float* __restrict__ b_ih1, const float* __restrict__ b_hh1,
                  const float* __restrict__ w_ih2, const float* __restrict__ w_hh2,
                  const float* __restrict__ b_ih2, const float* __restrict__ b_hh2,
                  const float* __restrict__ w_ih3, const float* __restrict__ w_hh3,
                  const float* __restrict__ b_ih3, const float* __restrict__ b_hh3,
                  const float* __restrict__ w_lin, const float* __restrict__ b_lin,
                  float* __restrict__ out)
{
    // [parity][cell][pair][lane] packed-f16 h words. 3 KiB.
    __shared__ int lds[2][3][2][64];

    const int tid = threadIdx.x;
    const int w = tid >> 6;           // wave id 0..5
    const int lane = tid & 63;
    const int n = lane & 15;          // element col AND A-row m
    const int q = lane >> 4;          // quad
    const bool q3 = (q == 3);
    const int c = w >> 1, p = w & 1;

    // zero-init LDS (this IS the warmup state: zero fragments)
    for (int k = tid; k < 2 * 3 * 2 * 64; k += 384) ((int*)lds)[k] = 0;
    __syncthreads();

    // ---- A fragments for our cell, gate-pre-scaled ----
    const float* Wih = (c == 0) ? w_ih1 : (c == 1) ? w_ih2 : w_ih3;
    const float* Whh = (c == 0) ? w_hh1 : (c == 1) ? w_hh2 : w_hh3;
    const float* Bih = (c == 0) ? b_ih1 : (c == 1) ? b_ih2 : b_ih3;
    const float* Bhh = (c == 0) ? b_hh1 : (c == 1) ? b_hh2 : b_hh3;
    // gate order i,f,g,o: sigmoid rows scaled by -log2e, tanh row by +2log2e
    const float SC[4] = {-1.4426950408889634f, -1.4426950408889634f,
                          2.8853900817779268f, -1.4426950408889634f};
    half8 A0, A1, A2, A3;
    {
        half8 tA[4];
#pragma unroll
        for (int g = 0; g < 4; ++g) {
            half8 t = {};
#pragma unroll
            for (int j = 0; j < 8; ++j) {
                const int u = 4 * q + (j & 3);
                const bool isin = (j < 4);
                float v = 0.f;
                if (n < NH) {
                    const int r = g * NH + n;
                    if (c == 0) {
                        v = isin ? ((u < NH) ? Whh[r * NH + u] : Wih[r])
                                 : ((u < NH) ? 0.f : (Bih[r] + Bhh[r]));
                    } else {
                        v = isin ? ((u < NH) ? Wih[r * NH + u] : 0.f)
                                 : ((u < NH) ? Whh[r * NH + u]
                                             : (Bih[r] + Bhh[r]));
                    }
                }
                t[j] = (_Float16)(v * SC[g]);
            }
            tA[g] = t;
        }
        A0 = tA[0]; A1 = tA[1]; A2 = tA[2]; A3 = tA[3];
    }

    // head A-fragment (wave 5 only): row m=0 = w_lin over own-slots,
    // b_lin at k=31 (UNscaled - linear head)
    half8 ah = {};
    if (w == 5 && n == 0) {
#pragma unroll
        for (int j = 4; j < 8; ++j) {
            const int u = 4 * q + (j - 4);
            ah[j] = (_Float16)((u < NH) ? w_lin[u] : b_lin[0]);
        }
    }

    const float* xrow = input + (size_t)(blockIdx.x * 16 + n) * TT;
    float* orow = out + (size_t)(blockIdx.x * 16 + n) * TT;

    if      (w == 0) role_loop<0, 0, false>(lane, n, q, q3, lds, A0, A1, A2, A3, ah, xrow, orow);
    else if (w == 1) role_loop<0, 1, false>(lane, n, q, q3, lds, A0, A1, A2, A3, ah, xrow, orow);
    else if (w == 2) role_loop<1, 0, false>(lane, n, q, q3, lds, A0, A1, A2, A3, ah, xrow, orow);
    else if (w == 3) role_loop<1, 1, false>(lane, n, q, q3, lds, A0, A1, A2, A3, ah, xrow, orow);
    else if (w == 4) role_loop<2, 0, false>(lane, n, q, q3, lds, A0, A1, A2, A3, ah, xrow, orow);
    else             role_loop<2, 1, true >(lane, n, q, q3, lds, A0, A1, A2, A3, ah, xrow, orow);
}

extern "C" void kernel_launch(void* const* d_in, const int* in_sizes, int n_in,
                              void* d_out, int out_size, void* d_ws, size_t ws_size,
                              hipStream_t stream) {
    const float* input = (const float*)d_in[0];
    const float* w_ih1 = (const float*)d_in[1];
    const float* w_hh1 = (const float*)d_in[2];
    const float* b_ih1 = (const float*)d_in[3];
    const float* b_hh1 = (const float*)d_in[4];
    const float* w_ih2 = (const float*)d_in[5];
    const float* w_hh2 = (const float*)d_in[6];
    const float* b_ih2 = (const float*)d_in[7];
    const float* b_hh2 = (const float*)d_in[8];
    const float* w_ih3 = (const float*)d_in[9];
    const float* w_hh3 = (const float*)d_in[10];
    const float* b_ih3 = (const float*)d_in[11];
    const float* b_hh3 = (const float*)d_in[12];
    const float* w_lin = (const float*)d_in[13];
    const float* b_lin = (const float*)d_in[14];
    float* out = (float*)d_out;

    const int B = in_sizes[0] / TT;      // 8192
    const int blocks = B / 16;           // 512 blocks x 6 waves = 3072 waves

    lstm3_split6<<<blocks, 384, 0, stream>>>(
        input, w_ih1, w_hh1, b_ih1, b_hh1,
        w_ih2, w_hh2, b_ih2, b_hh2,
        w_ih3, w_hh3, b_ih3, b_hh3,
        w_lin, b_lin, out);
}

// Round 7
// 1117.015 us; speedup vs baseline: 1.1594x; 1.1594x over previous
//
#include <hip/hip_runtime.h>
#include <cstdint>

#define TT 2048
#define NH 15

typedef _Float16 half8 __attribute__((ext_vector_type(8)));
typedef float f32x4 __attribute__((ext_vector_type(4)));
typedef int int4v __attribute__((ext_vector_type(4)));

#define EXP2(x) __builtin_amdgcn_exp2f(x)
#define RCP(x) __builtin_amdgcn_rcpf(x)
#define BPERM(addr, v) __builtin_amdgcn_ds_bpermute((addr), (v))
#define PKRTZ_I(a, b) __builtin_bit_cast(int, __builtin_amdgcn_cvt_pkrtz((a), (b)))
#define MFMA16(A, B, C) __builtin_amdgcn_mfma_f32_16x16x32_f16((A), (B), (C), 0, 0, 0)

// Rational-fused gates on PRE-SCALED mfma outputs:
//   d0 = -zi*log2e, d1 = -zf*log2e, d2 = +2*zg*log2e, d3 = -zo*log2e
//   ui=2^d0=e^-zi, uf=e^-zf, sg=e^{2zg}, uo=e^-zo
//   i=1/(1+ui), f=1/(1+uf), g=(sg-1)/(sg+1), o=1/(1+uo)
//   c' = f*c + i*g = [c*(1+ui)(sg+1) + (1+uf)(sg-1)] / [(1+uf)(1+ui)(sg+1)]
//   h  = o*tanh(c') = (sc-1) / ((1+uo)(sc+1)),  sc = e^{2c'}
// 6 trans (4 exp2 + 2 rcp) + ~13 VALU, vs 10 trans + ~13 VALU before.
#define GATES_RAT(d0, d1, d2, d3, cref, hout) { \
    const float ui_ = EXP2(d0); \
    const float uf_ = EXP2(d1); \
    const float sg_ = EXP2(d2); \
    const float uo_ = EXP2(d3); \
    const float a_  = 1.0f + ui_; \
    const float b_  = 1.0f + sg_; \
    const float e_  = 1.0f + uf_; \
    const float ab_ = a_ * b_; \
    const float num_ = fmaf((cref), ab_, e_ * (sg_ - 1.0f)); \
    (cref) = num_ * RCP(ab_ * e_); \
    const float sc_ = EXP2((cref) * 2.8853900817779268f); \
    (hout) = (sc_ - 1.0f) * RCP((1.0f + uo_) * (sc_ + 1.0f)); }

// raw barrier: LDS-ordering only (no vmcnt drain of x-prefetch / out-stores)
#define LDS_BAR() { asm volatile("s_waitcnt lgkmcnt(0)" ::: "memory"); \
                    __builtin_amdgcn_s_barrier(); }

// 2-wave cell-split, layer-wavefront staggered MFMA LSTM (R4 skeleton).
// Block = 128 threads = 2 waves, one 16-element batch tile.
//   wave A: cell1 (full) + cell3 gate-rows r=0,1
//   wave B: cell2 (full) + cell3 gate-rows r=2,3 + head (extra MFMA row)
// 1024 waves = 1 wave/SIMD on all 1024 SIMDs.
//
// Fragment maps (m89-verified): A[m=lane&15][k=(lane>>4)*8+j];
// B[k][n=lane&15]; D col=lane&15, row=(lane>>4)*4+r.
// Interleaved-K: k=8q+j: j<4 "in" unit 4q+j (cell1: u15=x), j>=4 "own"
// unit 4q+j-4 (u15 = bias 1.0). B-fragment dwords are lane-local packed
// f16 pairs; cross-wave exchange = 3 LDS words each way per step
// (parity double-buffer, 1 barrier/step).
//
// Stagger at iter i: A: h1(i), h3(i-2)[r01]; B: h2(i-1), h3(i-2)[r23],
// y(i-3) via head MFMA (w_lin on own-slots of cell3 B-frag, b_lin at k31).
// Warmup: zero-init LDS/regs => zero fragments => states stay exactly 0;
// cell3 bias word gated at the single (t0==0, ph==0) write.
// Tail iters (i>=TT) compute finite garbage never stored.
__global__ __launch_bounds__(128) __attribute__((amdgpu_waves_per_eu(1, 1)))
void lstm3_split(const float* __restrict__ input,
                 const float* __restrict__ w_ih1, const float* __restrict__ w_hh1,
                 const float* __restrict__ b_ih1, const float* __restrict__ b_hh1,
                 const float* __restrict__ w_ih2, const float* __restrict__ w_hh2,
                 const float* __restrict__ b_ih2, const float* __restrict__ b_hh2,
                 const float* __restrict__ w_ih3, const float* __restrict__ w_hh3,
                 const float* __restrict__ b_ih3, const float* __restrict__ b_hh3,
                 const float* __restrict__ w_lin, const float* __restrict__ b_lin,
                 float* __restrict__ out)
{
    // [parity][wave][slot][lane] dwords; slot-major -> lane-contiguous. 3 KiB.
    __shared__ int lds[2][2][3][64];

    const int tid = threadIdx.x;
    const int w = tid >> 6;           // 0 = wave A, 1 = wave B
    const int lane = tid & 63;
    const int n = lane & 15;          // element col AND A-row m
    const int q = lane >> 4;          // quad
    const bool q3 = (q == 3);

    // zero-init LDS (this IS the warmup state: zero fragments)
    for (int k = tid; k < 2 * 2 * 3 * 64; k += 128) ((int*)lds)[k] = 0;
    __syncthreads();

    const f32x4 z4 = {0.f, 0.f, 0.f, 0.f};
    // gate order i,f,g,o: sigmoid rows scaled by -log2e, tanh row by +2log2e
    const float SC[4] = {-1.4426950408889634f, -1.4426950408889634f,
                          2.8853900817779268f, -1.4426950408889634f};

    if (w == 0) {
        // ================= wave A: cell1 + cell3[r01] =================
        half8 a1[4], a3[4];
#pragma unroll
        for (int g = 0; g < 4; ++g) {
            half8 t1 = {}, t3 = {};
#pragma unroll
            for (int j = 0; j < 8; ++j) {
                const int u = 4 * q + (j & 3);
                const bool isin = (j < 4);
                float v1 = 0.f, v3 = 0.f;
                if (n < NH) {
                    const int r = g * NH + n;
                    if (isin) {
                        v1 = (u < NH) ? w_hh1[r * NH + u] : w_ih1[r];
                        v3 = (u < NH) ? w_ih3[r * NH + u] : 0.f;
                    } else {
                        v1 = (u < NH) ? 0.f : (b_ih1[r] + b_hh1[r]);
                        v3 = (u < NH) ? w_hh3[r * NH + u] : (b_ih3[r] + b_hh3[r]);
                    }
                }
                t1[j] = (_Float16)(v1 * SC[g]); t3[j] = (_Float16)(v3 * SC[g]);
            }
            a1[g] = t1; a3[g] = t3;
        }

        float h1f[4] = {0.f, 0.f, 0.f, 0.f}, c1f[4] = {0.f, 0.f, 0.f, 0.f};
        float c3a0 = 0.f, c3a1 = 0.f;
        int pA3k = 0;                     // kept pk(h3[0],h3[1]) of last iter
        const int b1w3 = q3 ? 0x3C000000 : 0;   // cell1 bias word (hoisted)

        const float* xrow = input + (size_t)(blockIdx.x * 16 + n) * TT;
        float xtile = xrow[q];
        float xtile_n = xrow[4 + q];
        // packed x: hi16 of the dword = f16(x); bcast pulls the whole word
        int xp = PKRTZ_I(0.f, xtile);
        int xp_n = PKRTZ_I(0.f, xtile_n);
        int xvp = BPERM(n * 4, xp);       // x(0) broadcast (phase 0)

#pragma unroll 1
        for (int t0 = 0; t0 < TT + 4; t0 += 4) {
#pragma unroll
            for (int ph = 0; ph < 4; ++ph) {
                const int p = (t0 + ph) & 1, pr = p ^ 1;
                // ---- read B's packs (written last iter) ----
                const int rA2 = lds[pr][1][0][lane];
                const int rB2 = lds[pr][1][1][lane];
                const int rB3 = lds[pr][1][2][lane];
                // ---- x broadcast for next iter ----
                const int xps = (ph == 3) ? xp_n : xp;
                const int xvp_n = BPERM(((ph + 1) & 3) * 64 + n * 4, xps);
                // ---- fragments ----
                const int pA1 = PKRTZ_I(h1f[0], h1f[1]);
                const int pB1 = PKRTZ_I(h1f[2], h1f[3]);
                const int b1w1 = q3
                    ? (int)((pB1 & 0xFFFF) | (xvp & (int)0xFFFF0000))
                    : pB1;
                const int4v b1 = { pA1, b1w1, 0, b1w3 };
                const int4v b3 = { rA2, rB2, pA3k, rB3 };
                const half8 B1 = __builtin_bit_cast(half8, b1);
                const half8 B3 = __builtin_bit_cast(half8, b3);
                // ---- MFMAs ----
                f32x4 D10 = MFMA16(a1[0], B1, z4);
                f32x4 D11 = MFMA16(a1[1], B1, z4);
                f32x4 D12 = MFMA16(a1[2], B1, z4);
                f32x4 D13 = MFMA16(a1[3], B1, z4);
                f32x4 D30 = MFMA16(a3[0], B3, z4);
                f32x4 D31 = MFMA16(a3[1], B3, z4);
                f32x4 D32 = MFMA16(a3[2], B3, z4);
                f32x4 D33 = MFMA16(a3[3], B3, z4);
                // ---- gates: cell1 r0..3 ----
                GATES_RAT(D10[0], D11[0], D12[0], D13[0], c1f[0], h1f[0]);
                GATES_RAT(D10[1], D11[1], D12[1], D13[1], c1f[1], h1f[1]);
                GATES_RAT(D10[2], D11[2], D12[2], D13[2], c1f[2], h1f[2]);
                GATES_RAT(D10[3], D11[3], D12[3], D13[3], c1f[3], h1f[3]);
                // ---- gates: cell3 r0,1 ----
                float h3a0, h3a1;
                GATES_RAT(D30[0], D31[0], D32[0], D33[0], c3a0, h3a0);
                GATES_RAT(D30[1], D31[1], D32[1], D33[1], c3a1, h3a1);
                // ---- producer packs + write ----
                const int wA1 = PKRTZ_I(h1f[0], h1f[1]);
                const int wB1 = PKRTZ_I(h1f[2], h1f[3]);
                const int wA3 = PKRTZ_I(h3a0, h3a1);
                lds[p][0][0][lane] = wA1;
                lds[p][0][1][lane] = wB1;
                lds[p][0][2][lane] = wA3;
                pA3k = wA3;
                xvp = xvp_n;
                LDS_BAR();
            }
            xtile = xtile_n; xp = xp_n;
            const int tn = t0 + 8 + q;
            xtile_n = xrow[(tn < TT) ? tn : q];
            xp_n = PKRTZ_I(0.f, xtile_n);
        }
    } else {
        // ============ wave B: cell2 + cell3[r23] + head ============
        half8 a2[4], a3[4];
#pragma unroll
        for (int g = 0; g < 4; ++g) {
            half8 t2 = {}, t3 = {};
#pragma unroll
            for (int j = 0; j < 8; ++j) {
                const int u = 4 * q + (j & 3);
                const bool isin = (j < 4);
                float v2 = 0.f, v3 = 0.f;
                if (n < NH) {
                    const int r = g * NH + n;
                    if (isin) {
                        v2 = (u < NH) ? w_ih2[r * NH + u] : 0.f;
                        v3 = (u < NH) ? w_ih3[r * NH + u] : 0.f;
                    } else {
                        v2 = (u < NH) ? w_hh2[r * NH + u] : (b_ih2[r] + b_hh2[r]);
                        v3 = (u < NH) ? w_hh3[r * NH + u] : (b_ih3[r] + b_hh3[r]);
                    }
                }
                t2[j] = (_Float16)(v2 * SC[g]); t3[j] = (_Float16)(v3 * SC[g]);
            }
            a2[g] = t2; a3[g] = t3;
        }
        // head A-fragment: row m=0 = w_lin over own-slots, b_lin at k=31
        // (UNscaled - linear head). Dh[0] on q==0 lanes = y for column n.
        half8 ah = {};
        if (n == 0) {
#pragma unroll
            for (int j = 4; j < 8; ++j) {
                const int u = 4 * q + (j - 4);
                ah[j] = (_Float16)((u < NH) ? w_lin[u] : b_lin[0]);
            }
        }

        float c2f[4] = {0.f, 0.f, 0.f, 0.f};
        float c3b2 = 0.f, c3b3 = 0.f;
        int pA2k = 0, pB2k = 0;   // kept raw pk(h2) (cell2-own + cell3-in)
        int ov2k = 0;             // kept q3 bias variant for cell2 own-word1
        int ov3k = 0;             // kept q3 bias variant for cell3 own-word1
        float y4[4] = {0.f, 0.f, 0.f, 0.f};

        float* orow = out + (size_t)(blockIdx.x * 16 + n) * TT;

#pragma unroll 1
        for (int t0 = 0; t0 < TT + 4; t0 += 4) {
#pragma unroll
            for (int ph = 0; ph < 4; ++ph) {
                const int p = (t0 + ph) & 1, pr = p ^ 1;
                // ---- read A's packs (written last iter) ----
                const int rA1 = lds[pr][0][0][lane];
                const int rB1 = lds[pr][0][1][lane];
                const int rA3 = lds[pr][0][2][lane];
                // ---- fragments ----
                const int4v b2 = { rA1, rB1, pA2k, ov2k };
                const int4v b3 = { pA2k, pB2k, rA3, ov3k };
                const half8 B2 = __builtin_bit_cast(half8, b2);
                const half8 B3 = __builtin_bit_cast(half8, b3);
                // ---- MFMAs ----
                f32x4 D20 = MFMA16(a2[0], B2, z4);
                f32x4 D21 = MFMA16(a2[1], B2, z4);
                f32x4 D22 = MFMA16(a2[2], B2, z4);
                f32x4 D23 = MFMA16(a2[3], B2, z4);
                f32x4 D30 = MFMA16(a3[0], B3, z4);
                f32x4 D31 = MFMA16(a3[1], B3, z4);
                f32x4 D32 = MFMA16(a3[2], B3, z4);
                f32x4 D33 = MFMA16(a3[3], B3, z4);
                f32x4 Dh  = MFMA16(ah,    B3, z4);     // y(i-3) in q0/r0
                // ---- gates: cell2 r0..3 ----
                float h2n0, h2n1, h2n2, h2n3;
                GATES_RAT(D20[0], D21[0], D22[0], D23[0], c2f[0], h2n0);
                GATES_RAT(D20[1], D21[1], D22[1], D23[1], c2f[1], h2n1);
                GATES_RAT(D20[2], D21[2], D22[2], D23[2], c2f[2], h2n2);
                GATES_RAT(D20[3], D21[3], D22[3], D23[3], c2f[3], h2n3);
                // ---- gates: cell3 r2,3 ----
                float h3b2, h3b3;
                GATES_RAT(D30[2], D31[2], D32[2], D33[2], c3b2, h3b2);
                GATES_RAT(D30[3], D31[3], D32[3], D33[3], c3b3, h3b3);
                // ---- head collect / store ----
                y4[(ph + 1) & 3] = Dh[0];
                if (ph == 2 && t0 >= 4 && q == 0) {
                    *(f32x4*)(orow + t0 - 4) =
                        (f32x4){y4[0], y4[1], y4[2], y4[3]};
                }
                // ---- producer packs + write ----
                const int wA2 = PKRTZ_I(h2n0, h2n1);
                const int wB2 = PKRTZ_I(h2n2, h2n3);
                const int nv2 = q3 ? (int)((wB2 & 0xFFFF) | 0x3C000000) : wB2;
                // bias for cell3 consumption next iter: off only at very first
                const int g3hi = (ph >= 1 || t0 > 0) ? 0x3C000000 : 0;
                const int pk3 = PKRTZ_I(h3b2, h3b3);
                const int wB3 = q3 ? (int)((pk3 & 0xFFFF) | g3hi) : pk3;
                lds[p][1][0][lane] = wA2;
                lds[p][1][1][lane] = wB2;
                lds[p][1][2][lane] = wB3;
                pA2k = wA2; pB2k = wB2; ov2k = nv2; ov3k = wB3;
                LDS_BAR();
            }
        }
    }
}

extern "C" void kernel_launch(void* const* d_in, const int* in_sizes, int n_in,
                              void* d_out, int out_size, void* d_ws, size_t ws_size,
                              hipStream_t stream) {
    const float* input = (const float*)d_in[0];
    const float* w_ih1 = (const float*)d_in[1];
    const float* w_hh1 = (const float*)d_in[2];
    const float* b_ih1 = (const float*)d_in[3];
    const float* b_hh1 = (const float*)d_in[4];
    const float* w_ih2 = (const float*)d_in[5];
    const float* w_hh2 = (const float*)d_in[6];
    const float* b_ih2 = (const float*)d_in[7];
    const float* b_hh2 = (const float*)d_in[8];
    const float* w_ih3 = (const float*)d_in[9];
    const float* w_hh3 = (const float*)d_in[10];
    const float* b_ih3 = (const float*)d_in[11];
    const float* b_hh3 = (const float*)d_in[12];
    const float* w_lin = (const float*)d_in[13];
    const float* b_lin = (const float*)d_in[14];
    float* out = (float*)d_out;

    const int B = in_sizes[0] / TT;      // 8192
    const int blocks = B / 16;           // 512 blocks x 2 waves = 1024 waves

    lstm3_split<<<blocks, 128, 0, stream>>>(
        input, w_ih1, w_hh1, b_ih1, b_hh1,
        w_ih2, w_hh2, b_ih2, b_hh2,
        w_ih3, w_hh3, b_ih3, b_hh3,
        w_lin, b_lin, out);
}